// Round 1
// baseline (1560.500 us; speedup 1.0000x reference)
//
#include <hip/hip_runtime.h>
#include <hip/hip_bf16.h>
#include <math.h>

// ---------------------------------------------------------------------------
// Actor network: conv(6->18,3x3) -> conv(18->18,3x3) -> maxpool2 ->
//                conv(18->18,3x3) -> conv(18->18,3x3) -> avgpool2 ->
//                flatten+concat -> 3044->64 tanh -> 64->64 tanh ->
//                per-sample expert (2x) 64->5 -> softmax
// No activation between convs => compose conv1*conv2 and conv3*conv4 into
// single 5x5 convs (weights precomputed on device each launch).
// ---------------------------------------------------------------------------

// workspace layout (floats)
#define OFF_W12   0                         // 18*6*25   = 2700
#define OFF_B12   2700                      // 18
#define OFF_W34   2720                      // 18*18*25  = 8100
#define OFF_B34   10820                     // 18
#define OFF_INTER 16384                     // 2048*18*30*30 = 33,177,600
#define OFF_FEATS (16384 + 2048*18*900)     // 2048*3044     =  6,234,112

// ---------------------------------------------------------------------------
// Weight composition: Weff[o,ci,u,v] = sum_m sum_{a+c=u, b+d=v} W2[o,m,a,b]*W1[m,ci,c,d]
//                     beff[o] = b2[o] + sum_m b1[m]*sum_{a,b} W2[o,m,a,b]
// ---------------------------------------------------------------------------
__global__ void wcomp_kernel(const float* __restrict__ c1w, const float* __restrict__ c1b,
                             const float* __restrict__ c2w, const float* __restrict__ c2b,
                             const float* __restrict__ c3w, const float* __restrict__ c3b,
                             const float* __restrict__ c4w, const float* __restrict__ c4b,
                             float* __restrict__ ws)
{
    int idx = blockIdx.x * blockDim.x + threadIdx.x;
    if (idx < 2700) {
        int o = idx / 150, rem = idx % 150;
        int ci = rem / 25, uv = rem % 25, u = uv / 5, v = uv % 5;
        float s = 0.f;
        for (int m = 0; m < 18; ++m)
            for (int a = 0; a < 3; ++a) {
                int c = u - a; if (c < 0 || c > 2) continue;
                for (int b2 = 0; b2 < 3; ++b2) {
                    int d = v - b2; if (d < 0 || d > 2) continue;
                    s += c2w[((o*18+m)*3+a)*3+b2] * c1w[((m*6+ci)*3+c)*3+d];
                }
            }
        ws[OFF_W12 + (o*6+ci)*25 + uv] = s;
    } else if (idx < 2718) {
        int o = idx - 2700;
        float s = c2b[o];
        for (int m = 0; m < 18; ++m) {
            float t = 0.f;
            for (int k = 0; k < 9; ++k) t += c2w[(o*18+m)*9 + k];
            s += c1b[m] * t;
        }
        ws[OFF_B12 + o] = s;
    } else if (idx < 2718 + 8100) {
        int j = idx - 2718;
        int o = j / 450, rem = j % 450;
        int ci = rem / 25, uv = rem % 25, u = uv / 5, v = uv % 5;
        float s = 0.f;
        for (int m = 0; m < 18; ++m)
            for (int a = 0; a < 3; ++a) {
                int c = u - a; if (c < 0 || c > 2) continue;
                for (int b2 = 0; b2 < 3; ++b2) {
                    int d = v - b2; if (d < 0 || d > 2) continue;
                    s += c4w[((o*18+m)*3+a)*3+b2] * c3w[((m*18+ci)*3+c)*3+d];
                }
            }
        ws[OFF_W34 + (o*18+ci)*25 + uv] = s;
    } else if (idx < 2718 + 8100 + 18) {
        int o = idx - 2718 - 8100;
        float s = c4b[o];
        for (int m = 0; m < 18; ++m) {
            float t = 0.f;
            for (int k = 0; k < 9; ++k) t += c4w[(o*18+m)*9 + k];
            s += c3b[m] * t;
        }
        ws[OFF_B34 + o] = s;
    }
}

// ---------------------------------------------------------------------------
// K1: 5x5 composite conv (6->18) on 64x64 + 2x2 maxpool -> inter[B,18,30,30]
// one block = one 10x10 pooled tile (3x3 tiles per image). input tile 24x24.
// thread task = 2 couts x (2x4 conv-pixel window) = one pooled 1x2 pair.
// ---------------------------------------------------------------------------
__global__ __launch_bounds__(256) void conv12_kernel(
    const float* __restrict__ states, const float* __restrict__ ws,
    float* __restrict__ inter)
{
    __shared__ float in_t[6][24][24];
    __shared__ float w_t[2700];
    __shared__ float b_t[18];
    const int tid = threadIdx.x;
    const int bid = blockIdx.x;
    const int b  = bid / 9;
    const int tt = bid % 9;
    const int ty = tt / 3, tx = tt % 3;
    const int iy0 = ty * 20, ix0 = tx * 20;

    for (int i = tid; i < 2700; i += 256) w_t[i] = ws[OFF_W12 + i];
    if (tid < 18) b_t[tid] = ws[OFF_B12 + tid];
    const float* sb = states + (size_t)b * (6 * 4096);
    for (int i = tid; i < 6*24*24; i += 256) {
        int ci = i / 576, rem = i % 576, y = rem / 24, x = rem % 24;
        in_t[ci][y][x] = sb[ci*4096 + (iy0+y)*64 + (ix0+x)];
    }
    __syncthreads();

    float* ib = inter + (size_t)b * 16200;
    for (int idx = tid; idx < 450; idx += 256) {
        int cp = idx / 50, rem = idx % 50;
        int pr = rem / 5, pc2 = rem % 5;
        int o0 = cp * 2;
        int R = pr * 2, C = pc2 * 4;
        float a0[2][4], a1[2][4];
        #pragma unroll
        for (int r2 = 0; r2 < 2; ++r2)
            #pragma unroll
            for (int x = 0; x < 4; ++x) { a0[r2][x] = 0.f; a1[r2][x] = 0.f; }

        for (int ci = 0; ci < 6; ++ci) {
            float w0[25], w1[25];
            const float* wp0 = &w_t[(o0*6 + ci) * 25];
            const float* wp1 = &w_t[((o0+1)*6 + ci) * 25];
            #pragma unroll
            for (int k = 0; k < 25; ++k) { w0[k] = wp0[k]; w1[k] = wp1[k]; }
            #pragma unroll
            for (int h = 0; h < 6; ++h) {
                float rv[8];
                #pragma unroll
                for (int j = 0; j < 8; ++j) rv[j] = in_t[ci][R+h][C+j];
                if (h < 5) {   // conv row 0 of window, kernel row u=h
                    #pragma unroll
                    for (int v = 0; v < 5; ++v)
                        #pragma unroll
                        for (int x = 0; x < 4; ++x) {
                            a0[0][x] = fmaf(rv[x+v], w0[h*5+v], a0[0][x]);
                            a1[0][x] = fmaf(rv[x+v], w1[h*5+v], a1[0][x]);
                        }
                }
                if (h >= 1) {  // conv row 1 of window, kernel row u=h-1
                    #pragma unroll
                    for (int v = 0; v < 5; ++v)
                        #pragma unroll
                        for (int x = 0; x < 4; ++x) {
                            a0[1][x] = fmaf(rv[x+v], w0[(h-1)*5+v], a0[1][x]);
                            a1[1][x] = fmaf(rv[x+v], w1[(h-1)*5+v], a1[1][x]);
                        }
                }
            }
        }
        int py = ty*10 + pr, px = tx*10 + pc2*2;
        float bb0 = b_t[o0], bb1 = b_t[o0+1];
        float m00 = fmaxf(fmaxf(a0[0][0], a0[0][1]), fmaxf(a0[1][0], a0[1][1])) + bb0;
        float m01 = fmaxf(fmaxf(a0[0][2], a0[0][3]), fmaxf(a0[1][2], a0[1][3])) + bb0;
        float m10 = fmaxf(fmaxf(a1[0][0], a1[0][1]), fmaxf(a1[1][0], a1[1][1])) + bb1;
        float m11 = fmaxf(fmaxf(a1[0][2], a1[0][3]), fmaxf(a1[1][2], a1[1][3])) + bb1;
        ib[o0*900 + py*30 + px]         = m00;
        ib[o0*900 + py*30 + px + 1]     = m01;
        ib[(o0+1)*900 + py*30 + px]     = m10;
        ib[(o0+1)*900 + py*30 + px + 1] = m11;
    }
}

// ---------------------------------------------------------------------------
// K2: 5x5 composite conv (18->18) on 30x30 + 2x2 avgpool -> feats[B, co*169+py*13+px]
// one block = 13-wide x R-row pooled strip (R = 5,5,3). cols padded to 32 (zeros).
// ---------------------------------------------------------------------------
__global__ __launch_bounds__(256) void conv34_kernel(
    const float* __restrict__ inter, const float* __restrict__ ws,
    float* __restrict__ feats)
{
    __shared__ float in_t[18][14][32];
    __shared__ float w_t[8100];
    __shared__ float b_t[18];
    const int tid = threadIdx.x;
    const int bid = blockIdx.x;
    const int b  = bid / 3;
    const int tz = bid % 3;
    const int pr0 = tz * 5;
    const int R = (tz < 2) ? 5 : 3;
    const int nrows = 2*R + 4;        // 14 or 10
    const int iy0 = pr0 * 2;

    for (int i = tid; i < 8100; i += 256) w_t[i] = ws[OFF_W34 + i];
    if (tid < 18) b_t[tid] = ws[OFF_B34 + tid];
    const float* ib = inter + (size_t)b * 16200;
    int tot = 18 * nrows * 32;
    for (int i = tid; i < tot; i += 256) {
        int ci = i / (nrows*32), rem = i % (nrows*32);
        int y = rem >> 5, x = rem & 31;
        in_t[ci][y][x] = (x < 30) ? ib[ci*900 + (iy0+y)*30 + x] : 0.f;
    }
    __syncthreads();

    float* fb = feats + (size_t)b * 3044;
    const int ntask = 9 * R * 7;
    for (int idx = tid; idx < ntask; idx += 256) {
        int cp = idx / (R*7), rem = idx % (R*7);
        int pr = rem / 7, pcb = rem % 7;
        int o0 = cp * 2;
        int Rl = pr * 2, C = pcb * 4;
        float a0[2][4], a1[2][4];
        #pragma unroll
        for (int r2 = 0; r2 < 2; ++r2)
            #pragma unroll
            for (int x = 0; x < 4; ++x) { a0[r2][x] = 0.f; a1[r2][x] = 0.f; }

        for (int ci = 0; ci < 18; ++ci) {
            float w0[25], w1[25];
            const float* wp0 = &w_t[(o0*18 + ci) * 25];
            const float* wp1 = &w_t[((o0+1)*18 + ci) * 25];
            #pragma unroll
            for (int k = 0; k < 25; ++k) { w0[k] = wp0[k]; w1[k] = wp1[k]; }
            #pragma unroll
            for (int h = 0; h < 6; ++h) {
                float rv[8];
                #pragma unroll
                for (int j = 0; j < 8; ++j) rv[j] = in_t[ci][Rl+h][C+j];
                if (h < 5) {
                    #pragma unroll
                    for (int v = 0; v < 5; ++v)
                        #pragma unroll
                        for (int x = 0; x < 4; ++x) {
                            a0[0][x] = fmaf(rv[x+v], w0[h*5+v], a0[0][x]);
                            a1[0][x] = fmaf(rv[x+v], w1[h*5+v], a1[0][x]);
                        }
                }
                if (h >= 1) {
                    #pragma unroll
                    for (int v = 0; v < 5; ++v)
                        #pragma unroll
                        for (int x = 0; x < 4; ++x) {
                            a0[1][x] = fmaf(rv[x+v], w0[(h-1)*5+v], a0[1][x]);
                            a1[1][x] = fmaf(rv[x+v], w1[(h-1)*5+v], a1[1][x]);
                        }
                }
            }
        }
        int py = pr0 + pr, pc = pcb * 2;
        float bb0 = b_t[o0], bb1 = b_t[o0+1];
        float f00 = 0.25f*(a0[0][0]+a0[0][1]+a0[1][0]+a0[1][1]) + bb0;
        float f10 = 0.25f*(a1[0][0]+a1[0][1]+a1[1][0]+a1[1][1]) + bb1;
        fb[o0*169 + py*13 + pc]     = f00;
        fb[(o0+1)*169 + py*13 + pc] = f10;
        if (pcb < 6) {
            float f01 = 0.25f*(a0[0][2]+a0[0][3]+a0[1][2]+a0[1][3]) + bb0;
            float f11 = 0.25f*(a1[0][2]+a1[0][3]+a1[1][2]+a1[1][3]) + bb1;
            fb[o0*169 + py*13 + pc + 1]     = f01;
            fb[(o0+1)*169 + py*13 + pc + 1] = f11;
        }
    }
}

// ---------------------------------------------------------------------------
// K3: MLP (3044->64 tanh -> 64->64 tanh -> expert 64->5 -> softmax)
// block = 8 batch rows. l1: thread = (k-segment ks of 8) x (2-rowgroup) x
// (16 out-group of 4) with 4x4 register tile; LDS reduce across ks.
// ---------------------------------------------------------------------------
__global__ __launch_bounds__(256) void mlp_kernel(
    const float* __restrict__ feats, const float* __restrict__ scores,
    const float* __restrict__ times, const int* __restrict__ agents,
    const float* __restrict__ l1w, const float* __restrict__ l1b,
    const float* __restrict__ l2w, const float* __restrict__ l2b,
    const float* __restrict__ agw, const float* __restrict__ agb,
    float* __restrict__ out)
{
    __shared__ float x_t[8][129];
    __shared__ float w_t[64][129];
    __shared__ float red[8][32][17];
    __shared__ float h1_t[8][65];
    __shared__ float h2_t[8][65];
    const int tid = threadIdx.x;
    const int b0 = blockIdx.x * 8;
    const int slot = tid & 31;
    const int ks = tid >> 5;     // 0..7 k-segment
    const int rg = slot & 1;     // rows rg*4 .. rg*4+3
    const int og = slot >> 1;    // outputs og*4 .. og*4+3

    float acc[4][4];
    #pragma unroll
    for (int i = 0; i < 4; ++i)
        #pragma unroll
        for (int j = 0; j < 4; ++j) acc[i][j] = 0.f;

    for (int c = 0; c < 24; ++c) {
        int k0 = c * 128;
        int klen = (3044 - k0 < 128) ? (3044 - k0) : 128;
        for (int i = tid; i < 8*128; i += 256) {
            int row = i >> 7, col = i & 127;
            int g = k0 + col;
            float v = 0.f;
            if (col < klen)
                v = (g < 3042) ? feats[(size_t)(b0+row)*3044 + g]
                               : ((g == 3042) ? scores[b0+row] : times[b0+row]);
            x_t[row][col] = v;
        }
        for (int i = tid; i < 64*32; i += 256) {
            int row = i >> 5, c4 = (i & 31) * 4;
            float4 v = make_float4(0.f, 0.f, 0.f, 0.f);
            if (c4 + 4 <= klen)
                v = *(const float4*)&l1w[(size_t)row*3044 + k0 + c4];
            w_t[row][c4+0] = v.x; w_t[row][c4+1] = v.y;
            w_t[row][c4+2] = v.z; w_t[row][c4+3] = v.w;
        }
        __syncthreads();
        #pragma unroll 4
        for (int kk = 0; kk < 16; ++kk) {
            int k = ks*16 + kk;
            float xv[4], wv[4];
            #pragma unroll
            for (int j = 0; j < 4; ++j) xv[j] = x_t[rg*4+j][k];
            #pragma unroll
            for (int j = 0; j < 4; ++j) wv[j] = w_t[og*4+j][k];
            #pragma unroll
            for (int jr = 0; jr < 4; ++jr)
                #pragma unroll
                for (int jo = 0; jo < 4; ++jo)
                    acc[jr][jo] = fmaf(xv[jr], wv[jo], acc[jr][jo]);
        }
        __syncthreads();
    }
    #pragma unroll
    for (int jr = 0; jr < 4; ++jr)
        #pragma unroll
        for (int jo = 0; jo < 4; ++jo)
            red[ks][slot][jr*4+jo] = acc[jr][jo];
    __syncthreads();
    if (tid < 32) {
        int s_rg = tid & 1, s_og = tid >> 1;
        #pragma unroll
        for (int jr = 0; jr < 4; ++jr)
            #pragma unroll
            for (int jo = 0; jo < 4; ++jo) {
                float s = 0.f;
                #pragma unroll
                for (int k2 = 0; k2 < 8; ++k2) s += red[k2][tid][jr*4+jo];
                int r = s_rg*4 + jr, o = s_og*4 + jo;
                h1_t[r][o] = tanhf(s + l1b[o]);
            }
    }
    for (int i = tid; i < 64*64; i += 256) {
        int row = i >> 6, col = i & 63;
        w_t[row][col] = l2w[i];
    }
    __syncthreads();
    {
        int r = tid & 7, od = tid >> 3;   // od 0..31, outputs od*2, od*2+1
        float s0 = l2b[od*2], s1 = l2b[od*2+1];
        for (int k = 0; k < 64; ++k) {
            float hv = h1_t[r][k];
            s0 = fmaf(hv, w_t[od*2][k], s0);
            s1 = fmaf(hv, w_t[od*2+1][k], s1);
        }
        h2_t[r][od*2]   = tanhf(s0);
        h2_t[r][od*2+1] = tanhf(s1);
    }
    __syncthreads();
    if (tid < 8) {
        int gb = b0 + tid;
        int a = agents[gb];
        float lg[5];
        #pragma unroll
        for (int o = 0; o < 5; ++o) {
            float s = agb[a*5 + o];
            const float* wp = agw + (size_t)(a*5 + o) * 64;
            for (int d = 0; d < 64; ++d) s = fmaf(h2_t[tid][d], wp[d], s);
            lg[o] = s;
        }
        float m = lg[0];
        #pragma unroll
        for (int o = 1; o < 5; ++o) m = fmaxf(m, lg[o]);
        float e[5], sum = 0.f;
        #pragma unroll
        for (int o = 0; o < 5; ++o) { e[o] = expf(lg[o] - m); sum += e[o]; }
        float inv = 1.f / sum;
        #pragma unroll
        for (int o = 0; o < 5; ++o) out[gb*5 + o] = e[o] * inv;
    }
}

// ---------------------------------------------------------------------------
extern "C" void kernel_launch(void* const* d_in, const int* in_sizes, int n_in,
                              void* d_out, int out_size, void* d_ws, size_t ws_size,
                              hipStream_t stream)
{
    const float* states = (const float*)d_in[0];
    const float* scores = (const float*)d_in[1];
    const float* times  = (const float*)d_in[2];
    const int*   agents = (const int*)d_in[3];
    const float* c1w = (const float*)d_in[4];
    const float* c1b = (const float*)d_in[5];
    const float* c2w = (const float*)d_in[6];
    const float* c2b = (const float*)d_in[7];
    const float* c3w = (const float*)d_in[8];
    const float* c3b = (const float*)d_in[9];
    const float* c4w = (const float*)d_in[10];
    const float* c4b = (const float*)d_in[11];
    const float* l1w = (const float*)d_in[12];
    const float* l1b = (const float*)d_in[13];
    const float* l2w = (const float*)d_in[14];
    const float* l2b = (const float*)d_in[15];
    const float* agw = (const float*)d_in[16];
    const float* agb = (const float*)d_in[17];
    float* outp = (float*)d_out;
    float* ws = (float*)d_ws;

    hipLaunchKernelGGL(wcomp_kernel, dim3(43), dim3(256), 0, stream,
                       c1w, c1b, c2w, c2b, c3w, c3b, c4w, c4b, ws);
    hipLaunchKernelGGL(conv12_kernel, dim3(2048*9), dim3(256), 0, stream,
                       states, ws, ws + OFF_INTER);
    hipLaunchKernelGGL(conv34_kernel, dim3(2048*3), dim3(256), 0, stream,
                       ws + OFF_INTER, ws, ws + OFF_FEATS);
    hipLaunchKernelGGL(mlp_kernel, dim3(256), dim3(256), 0, stream,
                       ws + OFF_FEATS, scores, times, agents,
                       l1w, l1b, l2w, l2b, agw, agb, outp);
}

// Round 2
// 1133.177 us; speedup vs baseline: 1.3771x; 1.3771x over previous
//
#include <hip/hip_runtime.h>
#include <hip/hip_bf16.h>
#include <math.h>

// ---------------------------------------------------------------------------
// Actor network: conv(6->18,3x3) -> conv(18->18,3x3) -> maxpool2 ->
//                conv(18->18,3x3) -> conv(18->18,3x3) -> avgpool2 ->
//                flatten+concat -> 3044->64 tanh -> 64->64 tanh ->
//                per-sample expert (2x) 64->5 -> softmax
// Convs composed pairwise into 5x5 convs (no activation between them).
// LDS-free conv: weights are wave-uniform (every lane computes all 18 couts)
// -> scalar s_load path; inputs read from global (L1/L2) into a 6x6 register
// patch; one thread = one pooled output pixel.
// ---------------------------------------------------------------------------

// workspace layout (floats)
#define OFF_W12   0                         // [ci][u][v][o] : 6*25*18  = 2700
#define OFF_B12   2700                      // 18
#define OFF_W34   2720                      // [ci][u][v][o] : 18*25*18 = 8100
#define OFF_B34   10820                     // 18
#define OFF_INTER 16384                     // [b][co][py][px] 2048*18*900
#define OFF_FEATS (16384 + 2048*18*900)     // [b][3044]

// ---------------------------------------------------------------------------
__global__ void wcomp_kernel(const float* __restrict__ c1w, const float* __restrict__ c1b,
                             const float* __restrict__ c2w, const float* __restrict__ c2b,
                             const float* __restrict__ c3w, const float* __restrict__ c3b,
                             const float* __restrict__ c4w, const float* __restrict__ c4b,
                             float* __restrict__ ws)
{
    int idx = blockIdx.x * blockDim.x + threadIdx.x;
    if (idx < 2700) {
        int o = idx / 150, rem = idx % 150;
        int ci = rem / 25, uv = rem % 25, u = uv / 5, v = uv % 5;
        float s = 0.f;
        for (int m = 0; m < 18; ++m)
            for (int a = 0; a < 3; ++a) {
                int c = u - a; if (c < 0 || c > 2) continue;
                for (int b2 = 0; b2 < 3; ++b2) {
                    int d = v - b2; if (d < 0 || d > 2) continue;
                    s += c2w[((o*18+m)*3+a)*3+b2] * c1w[((m*6+ci)*3+c)*3+d];
                }
            }
        ws[OFF_W12 + (ci*25 + uv)*18 + o] = s;
    } else if (idx < 2718) {
        int o = idx - 2700;
        float s = c2b[o];
        for (int m = 0; m < 18; ++m) {
            float t = 0.f;
            for (int k = 0; k < 9; ++k) t += c2w[(o*18+m)*9 + k];
            s += c1b[m] * t;
        }
        ws[OFF_B12 + o] = s;
    } else if (idx < 2718 + 8100) {
        int j = idx - 2718;
        int o = j / 450, rem = j % 450;
        int ci = rem / 25, uv = rem % 25, u = uv / 5, v = uv % 5;
        float s = 0.f;
        for (int m = 0; m < 18; ++m)
            for (int a = 0; a < 3; ++a) {
                int c = u - a; if (c < 0 || c > 2) continue;
                for (int b2 = 0; b2 < 3; ++b2) {
                    int d = v - b2; if (d < 0 || d > 2) continue;
                    s += c4w[((o*18+m)*3+a)*3+b2] * c3w[((m*18+ci)*3+c)*3+d];
                }
            }
        ws[OFF_W34 + (ci*25 + uv)*18 + o] = s;
    } else if (idx < 2718 + 8100 + 18) {
        int o = idx - 2718 - 8100;
        float s = c4b[o];
        for (int m = 0; m < 18; ++m) {
            float t = 0.f;
            for (int k = 0; k < 9; ++k) t += c4w[(o*18+m)*9 + k];
            s += c3b[m] * t;
        }
        ws[OFF_B34 + o] = s;
    }
}

// ---------------------------------------------------------------------------
// K1: 5x5 conv (6->18) on 64x64 + 2x2 maxpool -> inter[b][18][30][30]
// thread = one pooled pixel (loops 4x: 900 pixels / 256 threads), all couts.
// ---------------------------------------------------------------------------
__global__ __launch_bounds__(256) void conv12_kernel(
    const float* __restrict__ states, const float* __restrict__ wall,
    float* __restrict__ inter)
{
    const int tid = threadIdx.x;
    const int b = blockIdx.x;
    const float* sb = states + (size_t)b * 24576;
    float* ib = inter + (size_t)b * 16200;

    float bias[18];
    #pragma unroll
    for (int o = 0; o < 18; ++o) bias[o] = wall[OFF_B12 + o];

    #pragma unroll 1
    for (int p = tid; p < 900; p += 256) {
        const int py = p / 30, px = p % 30;
        const float* ip0 = sb + (py * 2) * 64 + px * 2;
        float acc[18][4];
        #pragma unroll
        for (int o = 0; o < 18; ++o)
            #pragma unroll
            for (int j = 0; j < 4; ++j) acc[o][j] = 0.f;

        #pragma unroll 1
        for (int ci = 0; ci < 6; ++ci) {
            const float* ip = ip0 + ci * 4096;
            float pt[36];
            #pragma unroll
            for (int r = 0; r < 6; ++r)
                #pragma unroll
                for (int c = 0; c < 6; ++c)
                    pt[r * 6 + c] = ip[r * 64 + c];
            const float* wp = wall + OFF_W12 + ci * 450;
            #pragma unroll
            for (int u = 0; u < 5; ++u)
                #pragma unroll
                for (int v = 0; v < 5; ++v) {
                    const float p00 = pt[u*6 + v],     p01 = pt[u*6 + v + 1];
                    const float p10 = pt[(u+1)*6 + v], p11 = pt[(u+1)*6 + v + 1];
                    #pragma unroll
                    for (int o = 0; o < 18; ++o) {
                        const float w = wp[(u*5 + v)*18 + o];
                        acc[o][0] = fmaf(p00, w, acc[o][0]);
                        acc[o][1] = fmaf(p01, w, acc[o][1]);
                        acc[o][2] = fmaf(p10, w, acc[o][2]);
                        acc[o][3] = fmaf(p11, w, acc[o][3]);
                    }
                }
        }
        #pragma unroll
        for (int o = 0; o < 18; ++o) {
            float m = fmaxf(fmaxf(acc[o][0], acc[o][1]),
                            fmaxf(acc[o][2], acc[o][3])) + bias[o];
            ib[o * 900 + p] = m;
        }
    }
}

// ---------------------------------------------------------------------------
// K2: 5x5 conv (18->18) on 30x30 + 2x2 avgpool -> feats[b][co*169+py*13+px]
// thread = one pooled pixel (169 of 192 threads active), all couts.
// ---------------------------------------------------------------------------
__global__ __launch_bounds__(192) void conv34_kernel(
    const float* __restrict__ inter, const float* __restrict__ wall,
    float* __restrict__ feats)
{
    const int tid = threadIdx.x;
    const int b = blockIdx.x;
    if (tid >= 169) return;
    const int py = tid / 13, px = tid % 13;
    const float* ib0 = inter + (size_t)b * 16200 + (py * 2) * 30 + px * 2;
    float* fb = feats + (size_t)b * 3044;

    float acc[18][4];
    #pragma unroll
    for (int o = 0; o < 18; ++o)
        #pragma unroll
        for (int j = 0; j < 4; ++j) acc[o][j] = 0.f;

    #pragma unroll 1
    for (int ci = 0; ci < 18; ++ci) {
        const float* ip = ib0 + ci * 900;
        float pt[36];
        #pragma unroll
        for (int r = 0; r < 6; ++r)
            #pragma unroll
            for (int c = 0; c < 6; ++c)
                pt[r * 6 + c] = ip[r * 30 + c];
        const float* wp = wall + OFF_W34 + ci * 450;
        #pragma unroll
        for (int u = 0; u < 5; ++u)
            #pragma unroll
            for (int v = 0; v < 5; ++v) {
                const float p00 = pt[u*6 + v],     p01 = pt[u*6 + v + 1];
                const float p10 = pt[(u+1)*6 + v], p11 = pt[(u+1)*6 + v + 1];
                #pragma unroll
                for (int o = 0; o < 18; ++o) {
                    const float w = wp[(u*5 + v)*18 + o];
                    acc[o][0] = fmaf(p00, w, acc[o][0]);
                    acc[o][1] = fmaf(p01, w, acc[o][1]);
                    acc[o][2] = fmaf(p10, w, acc[o][2]);
                    acc[o][3] = fmaf(p11, w, acc[o][3]);
                }
            }
    }
    #pragma unroll
    for (int o = 0; o < 18; ++o) {
        float f = 0.25f * (acc[o][0] + acc[o][1] + acc[o][2] + acc[o][3])
                  + wall[OFF_B34 + o];
        fb[o * 169 + tid] = f;
    }
}

// ---------------------------------------------------------------------------
// K3: MLP (3044->64 tanh -> 64->64 tanh -> expert 64->5 -> softmax)
// ---------------------------------------------------------------------------
__global__ __launch_bounds__(256) void mlp_kernel(
    const float* __restrict__ feats, const float* __restrict__ scores,
    const float* __restrict__ times, const int* __restrict__ agents,
    const float* __restrict__ l1w, const float* __restrict__ l1b,
    const float* __restrict__ l2w, const float* __restrict__ l2b,
    const float* __restrict__ agw, const float* __restrict__ agb,
    float* __restrict__ out)
{
    __shared__ float x_t[8][129];
    __shared__ float w_t[64][129];
    __shared__ float red[8][32][17];
    __shared__ float h1_t[8][65];
    __shared__ float h2_t[8][65];
    const int tid = threadIdx.x;
    const int b0 = blockIdx.x * 8;
    const int slot = tid & 31;
    const int ks = tid >> 5;     // 0..7 k-segment
    const int rg = slot & 1;     // rows rg*4 .. rg*4+3
    const int og = slot >> 1;    // outputs og*4 .. og*4+3

    float acc[4][4];
    #pragma unroll
    for (int i = 0; i < 4; ++i)
        #pragma unroll
        for (int j = 0; j < 4; ++j) acc[i][j] = 0.f;

    for (int c = 0; c < 24; ++c) {
        int k0 = c * 128;
        int klen = (3044 - k0 < 128) ? (3044 - k0) : 128;
        for (int i = tid; i < 8*128; i += 256) {
            int row = i >> 7, col = i & 127;
            int g = k0 + col;
            float v = 0.f;
            if (col < klen)
                v = (g < 3042) ? feats[(size_t)(b0+row)*3044 + g]
                               : ((g == 3042) ? scores[b0+row] : times[b0+row]);
            x_t[row][col] = v;
        }
        for (int i = tid; i < 64*32; i += 256) {
            int row = i >> 5, c4 = (i & 31) * 4;
            float4 v = make_float4(0.f, 0.f, 0.f, 0.f);
            if (c4 + 4 <= klen)
                v = *(const float4*)&l1w[(size_t)row*3044 + k0 + c4];
            w_t[row][c4+0] = v.x; w_t[row][c4+1] = v.y;
            w_t[row][c4+2] = v.z; w_t[row][c4+3] = v.w;
        }
        __syncthreads();
        #pragma unroll 4
        for (int kk = 0; kk < 16; ++kk) {
            int k = ks*16 + kk;
            float xv[4], wv[4];
            #pragma unroll
            for (int j = 0; j < 4; ++j) xv[j] = x_t[rg*4+j][k];
            #pragma unroll
            for (int j = 0; j < 4; ++j) wv[j] = w_t[og*4+j][k];
            #pragma unroll
            for (int jr = 0; jr < 4; ++jr)
                #pragma unroll
                for (int jo = 0; jo < 4; ++jo)
                    acc[jr][jo] = fmaf(xv[jr], wv[jo], acc[jr][jo]);
        }
        __syncthreads();
    }
    #pragma unroll
    for (int jr = 0; jr < 4; ++jr)
        #pragma unroll
        for (int jo = 0; jo < 4; ++jo)
            red[ks][slot][jr*4+jo] = acc[jr][jo];
    __syncthreads();
    if (tid < 32) {
        int s_rg = tid & 1, s_og = tid >> 1;
        #pragma unroll
        for (int jr = 0; jr < 4; ++jr)
            #pragma unroll
            for (int jo = 0; jo < 4; ++jo) {
                float s = 0.f;
                #pragma unroll
                for (int k2 = 0; k2 < 8; ++k2) s += red[k2][tid][jr*4+jo];
                int r = s_rg*4 + jr, o = s_og*4 + jo;
                h1_t[r][o] = tanhf(s + l1b[o]);
            }
    }
    for (int i = tid; i < 64*64; i += 256) {
        int row = i >> 6, col = i & 63;
        w_t[row][col] = l2w[i];
    }
    __syncthreads();
    {
        int r = tid & 7, od = tid >> 3;   // od 0..31, outputs od*2, od*2+1
        float s0 = l2b[od*2], s1 = l2b[od*2+1];
        for (int k = 0; k < 64; ++k) {
            float hv = h1_t[r][k];
            s0 = fmaf(hv, w_t[od*2][k], s0);
            s1 = fmaf(hv, w_t[od*2+1][k], s1);
        }
        h2_t[r][od*2]   = tanhf(s0);
        h2_t[r][od*2+1] = tanhf(s1);
    }
    __syncthreads();
    if (tid < 8) {
        int gb = b0 + tid;
        int a = agents[gb];
        float lg[5];
        #pragma unroll
        for (int o = 0; o < 5; ++o) {
            float s = agb[a*5 + o];
            const float* wp = agw + (size_t)(a*5 + o) * 64;
            for (int d = 0; d < 64; ++d) s = fmaf(h2_t[tid][d], wp[d], s);
            lg[o] = s;
        }
        float m = lg[0];
        #pragma unroll
        for (int o = 1; o < 5; ++o) m = fmaxf(m, lg[o]);
        float e[5], sum = 0.f;
        #pragma unroll
        for (int o = 0; o < 5; ++o) { e[o] = expf(lg[o] - m); sum += e[o]; }
        float inv = 1.f / sum;
        #pragma unroll
        for (int o = 0; o < 5; ++o) out[gb*5 + o] = e[o] * inv;
    }
}

// ---------------------------------------------------------------------------
extern "C" void kernel_launch(void* const* d_in, const int* in_sizes, int n_in,
                              void* d_out, int out_size, void* d_ws, size_t ws_size,
                              hipStream_t stream)
{
    const float* states = (const float*)d_in[0];
    const float* scores = (const float*)d_in[1];
    const float* times  = (const float*)d_in[2];
    const int*   agents = (const int*)d_in[3];
    const float* c1w = (const float*)d_in[4];
    const float* c1b = (const float*)d_in[5];
    const float* c2w = (const float*)d_in[6];
    const float* c2b = (const float*)d_in[7];
    const float* c3w = (const float*)d_in[8];
    const float* c3b = (const float*)d_in[9];
    const float* c4w = (const float*)d_in[10];
    const float* c4b = (const float*)d_in[11];
    const float* l1w = (const float*)d_in[12];
    const float* l1b = (const float*)d_in[13];
    const float* l2w = (const float*)d_in[14];
    const float* l2b = (const float*)d_in[15];
    const float* agw = (const float*)d_in[16];
    const float* agb = (const float*)d_in[17];
    float* outp = (float*)d_out;
    float* ws = (float*)d_ws;

    hipLaunchKernelGGL(wcomp_kernel, dim3(43), dim3(256), 0, stream,
                       c1w, c1b, c2w, c2b, c3w, c3b, c4w, c4b, ws);
    hipLaunchKernelGGL(conv12_kernel, dim3(2048), dim3(256), 0, stream,
                       states, ws, ws + OFF_INTER);
    hipLaunchKernelGGL(conv34_kernel, dim3(2048), dim3(192), 0, stream,
                       ws + OFF_INTER, ws, ws + OFF_FEATS);
    hipLaunchKernelGGL(mlp_kernel, dim3(256), dim3(256), 0, stream,
                       ws + OFF_FEATS, scores, times, agents,
                       l1w, l1b, l2w, l2b, agw, agb, outp);
}

// Round 3
// 852.907 us; speedup vs baseline: 1.8296x; 1.3286x over previous
//
#include <hip/hip_runtime.h>
#include <hip/hip_bf16.h>
#include <math.h>

// ---------------------------------------------------------------------------
// Actor network. Convs composed pairwise into 5x5 convs (no activation
// between them). conv12 = fp16 MFMA implicit-GEMM (rolling-u accumulation),
// conv34 = fp32 VALU (ported next round), MLP fp32.
// ---------------------------------------------------------------------------

typedef _Float16 f16;
typedef f16 f16x8 __attribute__((ext_vector_type(8)));
typedef f16 f16x4 __attribute__((ext_vector_type(4)));
typedef float f32x16 __attribute__((ext_vector_type(16)));

// workspace layout (float units)
#define OFF_W12    0                        // [ci][uv][o] 6*25*18 = 2700 (fp32)
#define OFF_B12    2700                     // 18
#define OFF_W34    2720                     // [ci][uv][o] 18*25*18 = 8100
#define OFF_B34    10820                    // 18
#define OFF_B12PAD 10840                    // 32 (fp32, couts padded)
#define OFF_BF12   10880                    // f16 B-frags: 15*64*8 f16 = 3840 floats
#define OFF_INTER  16384                    // [b][co][py][px] 2048*18*900 fp32
#define OFF_FEATS  (16384 + 2048*18*900)    // [b][3044] fp32

// ---------------------------------------------------------------------------
// Weight composition (fp32): Weff[o,ci,u,v] = sum_m W2[o,m,a,b]*W1[m,ci,c,d]
// ---------------------------------------------------------------------------
__global__ void wcomp_kernel(const float* __restrict__ c1w, const float* __restrict__ c1b,
                             const float* __restrict__ c2w, const float* __restrict__ c2b,
                             const float* __restrict__ c3w, const float* __restrict__ c3b,
                             const float* __restrict__ c4w, const float* __restrict__ c4b,
                             float* __restrict__ ws)
{
    int idx = blockIdx.x * blockDim.x + threadIdx.x;
    if (idx < 2700) {
        int o = idx / 150, rem = idx % 150;
        int ci = rem / 25, uv = rem % 25, u = uv / 5, v = uv % 5;
        float s = 0.f;
        for (int m = 0; m < 18; ++m)
            for (int a = 0; a < 3; ++a) {
                int c = u - a; if (c < 0 || c > 2) continue;
                for (int b2 = 0; b2 < 3; ++b2) {
                    int d = v - b2; if (d < 0 || d > 2) continue;
                    s += c2w[((o*18+m)*3+a)*3+b2] * c1w[((m*6+ci)*3+c)*3+d];
                }
            }
        ws[OFF_W12 + (ci*25 + uv)*18 + o] = s;
    } else if (idx < 2718) {
        int o = idx - 2700;
        float s = c2b[o];
        for (int m = 0; m < 18; ++m) {
            float t = 0.f;
            for (int k = 0; k < 9; ++k) t += c2w[(o*18+m)*9 + k];
            s += c1b[m] * t;
        }
        ws[OFF_B12 + o] = s;
    } else if (idx < 2718 + 8100) {
        int j = idx - 2718;
        int o = j / 450, rem = j % 450;
        int ci = rem / 25, uv = rem % 25, u = uv / 5, v = uv % 5;
        float s = 0.f;
        for (int m = 0; m < 18; ++m)
            for (int a = 0; a < 3; ++a) {
                int c = u - a; if (c < 0 || c > 2) continue;
                for (int b2 = 0; b2 < 3; ++b2) {
                    int d = v - b2; if (d < 0 || d > 2) continue;
                    s += c4w[((o*18+m)*3+a)*3+b2] * c3w[((m*18+ci)*3+c)*3+d];
                }
            }
        ws[OFF_W34 + (ci*25 + uv)*18 + o] = s;
    } else if (idx < 2718 + 8100 + 18) {
        int o = idx - 2718 - 8100;
        float s = c4b[o];
        for (int m = 0; m < 18; ++m) {
            float t = 0.f;
            for (int k = 0; k < 9; ++k) t += c4w[(o*18+m)*9 + k];
            s += c3b[m] * t;
        }
        ws[OFF_B34 + o] = s;
    }
}

// ---------------------------------------------------------------------------
// wfrag: build f16 MFMA B-fragments for conv12 from composite W12.
// frag (u, c): lane l: co = l&31, kg = l>>5, v = 2*c+kg, ci = j (0..7).
// value = W12[ci][u*5+v][co] if (v<5, ci<6, co<18) else 0.
// ---------------------------------------------------------------------------
__global__ void wfrag_kernel(float* __restrict__ ws)
{
    int idx = blockIdx.x * blockDim.x + threadIdx.x;
    if (idx < 960) {
        int u = idx / 192, rem = idx % 192;
        int c = rem / 64, lane = rem % 64;
        int co = lane & 31, kg = lane >> 5;
        int v = 2*c + kg;
        f16x8 out;
        #pragma unroll
        for (int j = 0; j < 8; ++j) {
            float wv = 0.f;
            if (v < 5 && j < 6 && co < 18)
                wv = ws[OFF_W12 + (j*25 + u*5 + v)*18 + co];
            out[j] = (f16)wv;
        }
        ((f16x8*)(ws + OFF_BF12))[(u*3 + c)*64 + lane] = out;
    } else if (idx < 992) {
        int o = idx - 960;
        ws[OFF_B12PAD + o] = (o < 18) ? ws[OFF_B12 + o] : 0.f;
    }
}

// ---------------------------------------------------------------------------
// conv12_mfma: 5x5 composite conv (6->18) on 64x64 + 2x2 maxpool (fp16 MFMA)
// Grid = 2048 images x 4 bands (16 conv rows each, band 3 overlaps band 2).
// Block 256 = 4 waves; wave w = conv out-rows T..T+3 (T = B0 + 4w).
// LDS: im2col-friendly rows: lds[y][x*8 + ci] f16 (ci<6; slots 6,7 = 0),
// x-slots padded to 69 so A-reads stay in-row. A-frag (32x32x16):
// lane holds 8 slots = (v = 2c+kg, ci=0..7) at addr (px+v)*8 -> ds_read_b128.
// Rolling-u: A-row y = T+s feeds acc[s-u] for u in [max(0,s-3), min(4,s)].
// ---------------------------------------------------------------------------
#define LROW 552   // 69 px-slots * 8

__global__ __launch_bounds__(256, 2) void conv12_mfma(
    const float* __restrict__ states, const float* __restrict__ wall,
    float* __restrict__ inter)
{
    __shared__ __align__(16) f16 lds[20][LROW];
    const int tid  = threadIdx.x;
    const int lane = tid & 63;
    const int w    = tid >> 6;
    const int b    = blockIdx.x >> 2;
    const int band = blockIdx.x & 3;
    const int B0   = (band < 3) ? band * 16 : 44;
    const float* sb = states + (size_t)b * 24576;

    // preload B-frags (issue global loads early)
    f16x8 bf[15];
    const f16x8* bfp = (const f16x8*)(wall + OFF_BF12);
    #pragma unroll
    for (int i = 0; i < 15; ++i) bf[i] = bfp[i*64 + lane];
    const float bias_v = wall[OFF_B12PAD + (lane & 31)];

    // stage 20 input rows -> LDS f16 (channel-interleaved, stride 8)
    for (int t = tid; t < 320; t += 256) {
        int y = t >> 4, xq = (t & 15) * 4;
        const float* gp = sb + (size_t)(B0 + y) * 64 + xq;
        float4 v0 = *(const float4*)(gp);
        float4 v1 = *(const float4*)(gp + 4096);
        float4 v2 = *(const float4*)(gp + 8192);
        float4 v3 = *(const float4*)(gp + 12288);
        float4 v4 = *(const float4*)(gp + 16384);
        float4 v5 = *(const float4*)(gp + 20480);
        const float* A0 = (const float*)&v0;
        const float* A1 = (const float*)&v1;
        const float* A2 = (const float*)&v2;
        const float* A3 = (const float*)&v3;
        const float* A4 = (const float*)&v4;
        const float* A5 = (const float*)&v5;
        #pragma unroll
        for (int e = 0; e < 4; ++e) {
            f16x4 lo, hi;
            lo[0] = (f16)A0[e]; lo[1] = (f16)A1[e];
            lo[2] = (f16)A2[e]; lo[3] = (f16)A3[e];
            hi[0] = (f16)A4[e]; hi[1] = (f16)A5[e];
            hi[2] = (f16)0.f;   hi[3] = (f16)0.f;
            *(f16x4*)&lds[y][(xq + e)*8]     = lo;
            *(f16x4*)&lds[y][(xq + e)*8 + 4] = hi;
        }
    }
    // zero-fill x-slots 64..68
    for (int t = tid; t < 100; t += 256) {
        int y = t / 5, px = 64 + t % 5;
        f16x4 z; z[0] = (f16)0.f; z[1] = (f16)0.f; z[2] = (f16)0.f; z[3] = (f16)0.f;
        *(f16x4*)&lds[y][px*8]     = z;
        *(f16x4*)&lds[y][px*8 + 4] = z;
    }
    __syncthreads();

    const int T    = B0 + w*4;
    const int ln31 = lane & 31;
    const int kg   = lane >> 5;
    const int co   = ln31;
    float* ib = inter + (size_t)b * 16200;

    f32x16 acc[4][2];
    f32x16 zv = {0,0,0,0,0,0,0,0,0,0,0,0,0,0,0,0};
    #pragma unroll
    for (int i = 0; i < 4; ++i) { acc[i][0] = zv; acc[i][1] = zv; }
    float hold[2][8];

    #pragma unroll
    for (int s = 0; s < 8; ++s) {
        // A-frags for LDS row (w*4+s): 2 m-frags x 3 k-chunks
        f16x8 a[2][3];
        #pragma unroll
        for (int mf = 0; mf < 2; ++mf)
            #pragma unroll
            for (int c = 0; c < 3; ++c) {
                int xoff = mf*32 + ln31 + 2*c + kg;
                a[mf][c] = *(const f16x8*)&lds[w*4 + s][xoff*8];
            }
        const int ulo = (s > 3) ? s - 3 : 0;
        const int uhi = (s < 4) ? s : 4;
        #pragma unroll
        for (int u = 0; u <= 4; ++u) {
            if (u < ulo || u > uhi) continue;
            #pragma unroll
            for (int mf = 0; mf < 2; ++mf)
                #pragma unroll
                for (int c = 0; c < 3; ++c)
                    acc[s - u][mf] = __builtin_amdgcn_mfma_f32_32x32x16_f16(
                        a[mf][c], bf[u*3 + c], acc[s - u][mf], 0, 0, 0);
        }
        // conv row slot r = s-4 is complete: horizontal max, then pair rows
        if (s >= 4) {
            const int r = s - 4;
            #pragma unroll
            for (int mf = 0; mf < 2; ++mf) {
                float h[8];
                #pragma unroll
                for (int t2 = 0; t2 < 8; ++t2)
                    h[t2] = fmaxf(acc[r][mf][2*t2], acc[r][mf][2*t2 + 1]);
                if ((r & 1) == 0) {
                    #pragma unroll
                    for (int t2 = 0; t2 < 8; ++t2) hold[mf][t2] = h[t2];
                } else {
                    const int prow = (T + r) >> 1;
                    #pragma unroll
                    for (int t2 = 0; t2 < 8; ++t2) {
                        float val = fmaxf(hold[mf][t2], h[t2]) + bias_v;
                        int q = mf*16 + (t2 & 1) + (t2 >> 1)*4 + 2*kg;
                        if (co < 18 && q < 30)
                            ib[co*900 + prow*30 + q] = val;
                    }
                }
            }
        }
    }
}

// ---------------------------------------------------------------------------
// conv34 (fp32 VALU, unchanged): 5x5 conv (18->18) on 30x30 + avgpool
// ---------------------------------------------------------------------------
__global__ __launch_bounds__(192) void conv34_kernel(
    const float* __restrict__ inter, const float* __restrict__ wall,
    float* __restrict__ feats)
{
    const int tid = threadIdx.x;
    const int b = blockIdx.x;
    if (tid >= 169) return;
    const int py = tid / 13, px = tid % 13;
    const float* ib0 = inter + (size_t)b * 16200 + (py * 2) * 30 + px * 2;
    float* fb = feats + (size_t)b * 3044;

    float acc[18][4];
    #pragma unroll
    for (int o = 0; o < 18; ++o)
        #pragma unroll
        for (int j = 0; j < 4; ++j) acc[o][j] = 0.f;

    #pragma unroll 1
    for (int ci = 0; ci < 18; ++ci) {
        const float* ip = ib0 + ci * 900;
        float pt[36];
        #pragma unroll
        for (int r = 0; r < 6; ++r)
            #pragma unroll
            for (int c = 0; c < 6; ++c)
                pt[r * 6 + c] = ip[r * 30 + c];
        const float* wp = wall + OFF_W34 + ci * 450;
        #pragma unroll
        for (int u = 0; u < 5; ++u)
            #pragma unroll
            for (int v = 0; v < 5; ++v) {
                const float p00 = pt[u*6 + v],     p01 = pt[u*6 + v + 1];
                const float p10 = pt[(u+1)*6 + v], p11 = pt[(u+1)*6 + v + 1];
                #pragma unroll
                for (int o = 0; o < 18; ++o) {
                    const float w = wp[(u*5 + v)*18 + o];
                    acc[o][0] = fmaf(p00, w, acc[o][0]);
                    acc[o][1] = fmaf(p01, w, acc[o][1]);
                    acc[o][2] = fmaf(p10, w, acc[o][2]);
                    acc[o][3] = fmaf(p11, w, acc[o][3]);
                }
            }
    }
    #pragma unroll
    for (int o = 0; o < 18; ++o) {
        float f = 0.25f * (acc[o][0] + acc[o][1] + acc[o][2] + acc[o][3])
                  + wall[OFF_B34 + o];
        fb[o * 169 + tid] = f;
    }
}

// ---------------------------------------------------------------------------
// K3: MLP (3044->64 tanh -> 64->64 tanh -> expert 64->5 -> softmax)
// ---------------------------------------------------------------------------
__global__ __launch_bounds__(256) void mlp_kernel(
    const float* __restrict__ feats, const float* __restrict__ scores,
    const float* __restrict__ times, const int* __restrict__ agents,
    const float* __restrict__ l1w, const float* __restrict__ l1b,
    const float* __restrict__ l2w, const float* __restrict__ l2b,
    const float* __restrict__ agw, const float* __restrict__ agb,
    float* __restrict__ out)
{
    __shared__ float x_t[8][129];
    __shared__ float w_t[64][129];
    __shared__ float red[8][32][17];
    __shared__ float h1_t[8][65];
    __shared__ float h2_t[8][65];
    const int tid = threadIdx.x;
    const int b0 = blockIdx.x * 8;
    const int slot = tid & 31;
    const int ks = tid >> 5;
    const int rg = slot & 1;
    const int og = slot >> 1;

    float acc[4][4];
    #pragma unroll
    for (int i = 0; i < 4; ++i)
        #pragma unroll
        for (int j = 0; j < 4; ++j) acc[i][j] = 0.f;

    for (int c = 0; c < 24; ++c) {
        int k0 = c * 128;
        int klen = (3044 - k0 < 128) ? (3044 - k0) : 128;
        for (int i = tid; i < 8*128; i += 256) {
            int row = i >> 7, col = i & 127;
            int g = k0 + col;
            float v = 0.f;
            if (col < klen)
                v = (g < 3042) ? feats[(size_t)(b0+row)*3044 + g]
                               : ((g == 3042) ? scores[b0+row] : times[b0+row]);
            x_t[row][col] = v;
        }
        for (int i = tid; i < 64*32; i += 256) {
            int row = i >> 5, c4 = (i & 31) * 4;
            float4 v = make_float4(0.f, 0.f, 0.f, 0.f);
            if (c4 + 4 <= klen)
                v = *(const float4*)&l1w[(size_t)row*3044 + k0 + c4];
            w_t[row][c4+0] = v.x; w_t[row][c4+1] = v.y;
            w_t[row][c4+2] = v.z; w_t[row][c4+3] = v.w;
        }
        __syncthreads();
        #pragma unroll 4
        for (int kk = 0; kk < 16; ++kk) {
            int k = ks*16 + kk;
            float xv[4], wv[4];
            #pragma unroll
            for (int j = 0; j < 4; ++j) xv[j] = x_t[rg*4+j][k];
            #pragma unroll
            for (int j = 0; j < 4; ++j) wv[j] = w_t[og*4+j][k];
            #pragma unroll
            for (int jr = 0; jr < 4; ++jr)
                #pragma unroll
                for (int jo = 0; jo < 4; ++jo)
                    acc[jr][jo] = fmaf(xv[jr], wv[jo], acc[jr][jo]);
        }
        __syncthreads();
    }
    #pragma unroll
    for (int jr = 0; jr < 4; ++jr)
        #pragma unroll
        for (int jo = 0; jo < 4; ++jo)
            red[ks][slot][jr*4+jo] = acc[jr][jo];
    __syncthreads();
    if (tid < 32) {
        int s_rg = tid & 1, s_og = tid >> 1;
        #pragma unroll
        for (int jr = 0; jr < 4; ++jr)
            #pragma unroll
            for (int jo = 0; jo < 4; ++jo) {
                float s = 0.f;
                #pragma unroll
                for (int k2 = 0; k2 < 8; ++k2) s += red[k2][tid][jr*4+jo];
                int r = s_rg*4 + jr, o = s_og*4 + jo;
                h1_t[r][o] = tanhf(s + l1b[o]);
            }
    }
    for (int i = tid; i < 64*64; i += 256) {
        int row = i >> 6, col = i & 63;
        w_t[row][col] = l2w[i];
    }
    __syncthreads();
    {
        int r = tid & 7, od = tid >> 3;
        float s0 = l2b[od*2], s1 = l2b[od*2+1];
        for (int k = 0; k < 64; ++k) {
            float hv = h1_t[r][k];
            s0 = fmaf(hv, w_t[od*2][k], s0);
            s1 = fmaf(hv, w_t[od*2+1][k], s1);
        }
        h2_t[r][od*2]   = tanhf(s0);
        h2_t[r][od*2+1] = tanhf(s1);
    }
    __syncthreads();
    if (tid < 8) {
        int gb = b0 + tid;
        int a = agents[gb];
        float lg[5];
        #pragma unroll
        for (int o = 0; o < 5; ++o) {
            float s = agb[a*5 + o];
            const float* wp = agw + (size_t)(a*5 + o) * 64;
            for (int d = 0; d < 64; ++d) s = fmaf(h2_t[tid][d], wp[d], s);
            lg[o] = s;
        }
        float m = lg[0];
        #pragma unroll
        for (int o = 1; o < 5; ++o) m = fmaxf(m, lg[o]);
        float e[5], sum = 0.f;
        #pragma unroll
        for (int o = 0; o < 5; ++o) { e[o] = expf(lg[o] - m); sum += e[o]; }
        float inv = 1.f / sum;
        #pragma unroll
        for (int o = 0; o < 5; ++o) out[gb*5 + o] = e[o] * inv;
    }
}

// ---------------------------------------------------------------------------
extern "C" void kernel_launch(void* const* d_in, const int* in_sizes, int n_in,
                              void* d_out, int out_size, void* d_ws, size_t ws_size,
                              hipStream_t stream)
{
    const float* states = (const float*)d_in[0];
    const float* scores = (const float*)d_in[1];
    const float* times  = (const float*)d_in[2];
    const int*   agents = (const int*)d_in[3];
    const float* c1w = (const float*)d_in[4];
    const float* c1b = (const float*)d_in[5];
    const float* c2w = (const float*)d_in[6];
    const float* c2b = (const float*)d_in[7];
    const float* c3w = (const float*)d_in[8];
    const float* c3b = (const float*)d_in[9];
    const float* c4w = (const float*)d_in[10];
    const float* c4b = (const float*)d_in[11];
    const float* l1w = (const float*)d_in[12];
    const float* l1b = (const float*)d_in[13];
    const float* l2w = (const float*)d_in[14];
    const float* l2b = (const float*)d_in[15];
    const float* agw = (const float*)d_in[16];
    const float* agb = (const float*)d_in[17];
    float* outp = (float*)d_out;
    float* ws = (float*)d_ws;

    hipLaunchKernelGGL(wcomp_kernel, dim3(43), dim3(256), 0, stream,
                       c1w, c1b, c2w, c2b, c3w, c3b, c4w, c4b, ws);
    hipLaunchKernelGGL(wfrag_kernel, dim3(4), dim3(256), 0, stream, ws);
    hipLaunchKernelGGL(conv12_mfma, dim3(2048 * 4), dim3(256), 0, stream,
                       states, ws, ws + OFF_INTER);
    hipLaunchKernelGGL(conv34_kernel, dim3(2048), dim3(192), 0, stream,
                       ws + OFF_INTER, ws, ws + OFF_FEATS);
    hipLaunchKernelGGL(mlp_kernel, dim3(256), dim3(256), 0, stream,
                       ws + OFF_FEATS, scores, times, agents,
                       l1w, l1b, l2w, l2b, agw, agb, outp);
}